// Round 1
// 5961.148 us; speedup vs baseline: 1.5700x; 1.5700x over previous
//
#include <hip/hip_runtime.h>
#include <hip/hip_bf16.h>
#include <hip/hip_cooperative_groups.h>

namespace cg = cooperative_groups;

#define TB 4096   // T*B
#define NB 32     // B
#define NT 128    // T
#define H 256

// ---------------------------------------------------------------------------
// K1: conv1(8x8 s4) + relu + conv2(4x4 s2) + relu, fused per (img) block.
// x: [4096][4][84][84], out y2: [4096][2592] (channel-major flatten, matches
// reshape(N,-1) of [N,32,9,9]).  (unchanged from previous round)
// ---------------------------------------------------------------------------
__global__ __launch_bounds__(256) void conv_front(
    const float* __restrict__ x,
    const float* __restrict__ w1, const float* __restrict__ b1,
    const float* __restrict__ w2, const float* __restrict__ b2,
    float* __restrict__ y2)
{
    __shared__ float WBUF[8192];          // W1 uses 4096, then W2 uses 8192
    __shared__ float S1[6400];            // conv1 out [16][20][20]
    __shared__ float B1s[16], B2s[32];

    const int img = blockIdx.x;
    const int tid = threadIdx.x;

    for (int f = tid; f < 4096; f += 256) WBUF[f] = w1[f];
    if (tid < 16) B1s[tid] = b1[tid];
    if (tid < 32) B2s[tid] = b2[tid];
    __syncthreads();

    const float* xi = x + (size_t)img * 4 * 84 * 84;

    for (int pos = tid; pos < 400; pos += 256) {
        const int oy = pos / 20, ox = pos % 20;
        const int iy = oy * 4, ix = ox * 4;
        float acc[16];
        #pragma unroll
        for (int c = 0; c < 16; c++) acc[c] = B1s[c];
        for (int ci = 0; ci < 4; ci++) {
            #pragma unroll
            for (int ky = 0; ky < 8; ky++) {
                const float* xr = xi + ci * 7056 + (iy + ky) * 84 + ix;
                const float4 x0 = *(const float4*)(xr);
                const float4 x1 = *(const float4*)(xr + 4);
                #pragma unroll
                for (int co = 0; co < 16; co++) {
                    const float* wr = &WBUF[((co * 4 + ci) * 8 + ky) * 8];
                    const float4 wa = *(const float4*)(wr);
                    const float4 wb = *(const float4*)(wr + 4);
                    acc[co] += x0.x * wa.x + x0.y * wa.y + x0.z * wa.z + x0.w * wa.w
                             + x1.x * wb.x + x1.y * wb.y + x1.z * wb.z + x1.w * wb.w;
                }
            }
        }
        #pragma unroll
        for (int co = 0; co < 16; co++)
            S1[co * 400 + pos] = fmaxf(acc[co], 0.f);
    }
    __syncthreads();

    for (int f = tid; f < 8192; f += 256) WBUF[f] = w2[f];
    __syncthreads();

    if (tid < 243) {
        const int cgI = tid / 81, pos = tid % 81;
        const int co0 = cgI * 11;
        const int ncg = (cgI == 2) ? 10 : 11;
        const int oy = pos / 9, ox = pos % 9;
        const int iy = oy * 2, ix = ox * 2;
        float acc[11];
        #pragma unroll
        for (int c = 0; c < 11; c++) acc[c] = (c < ncg) ? B2s[co0 + c] : 0.f;
        for (int ci = 0; ci < 16; ci++) {
            #pragma unroll
            for (int ky = 0; ky < 4; ky++) {
                const float* sr = &S1[ci * 400 + (iy + ky) * 20 + ix];
                const float2 f0 = *(const float2*)(sr);
                const float2 f1 = *(const float2*)(sr + 2);
                for (int c = 0; c < ncg; c++) {
                    const float4 w4 = *(const float4*)&WBUF[((co0 + c) * 16 + ci) * 16 + ky * 4];
                    acc[c] += f0.x * w4.x + f0.y * w4.y + f1.x * w4.z + f1.y * w4.w;
                }
            }
        }
        float* yo = y2 + (size_t)img * 2592;
        for (int c = 0; c < ncg; c++)
            yo[(co0 + c) * 81 + pos] = fmaxf(acc[c], 0.f);
    }
}

// ---------------------------------------------------------------------------
// K2: register-tiled GEMM.  C[M,N] = act(A[M,K] @ W[N,K]^T + bias).
// Tile 64x64, BK=32, 256 threads, 4x4 accs/thread (tx = n-quad, ty = m-quad).
// AT: A is stored transposed [K][M] (read column-major A).
// CT: C is written transposed [N][M].
// LDS: As[k][m], Bs[k][n], stride 68 -> conflict-free b128 fragment reads.
// ---------------------------------------------------------------------------
__global__ __launch_bounds__(256) void gemm64(
    const float* __restrict__ A, const float* __restrict__ W,
    const float* __restrict__ bias, float* __restrict__ C,
    int M, int N, int K, int relu, int AT, int CT)
{
    __shared__ float As[32][68];   // [k][m]
    __shared__ float Bs[32][68];   // [k][n]
    const int tid = threadIdx.x;
    const int m0 = blockIdx.x * 64;
    const int n0 = blockIdx.y * 64;
    const int tx = tid & 15, ty = tid >> 4;

    float acc[4][4];
    #pragma unroll
    for (int i = 0; i < 4; i++)
        #pragma unroll
        for (int j = 0; j < 4; j++) acc[i][j] = 0.f;

    for (int k0 = 0; k0 < K; k0 += 32) {
        // ---- stage A tile into As[k][m] ----
        if (AT) {
            #pragma unroll
            for (int r = 0; r < 2; r++) {
                const int f = tid + r * 256;           // 0..511
                const int kk = f >> 4, m4 = (f & 15) << 2;
                float4 v = make_float4(0.f, 0.f, 0.f, 0.f);
                if (k0 + kk < K) v = *(const float4*)&A[(size_t)(k0 + kk) * M + m0 + m4];
                *(float4*)&As[kk][m4] = v;
            }
        } else {
            #pragma unroll
            for (int r = 0; r < 2; r++) {
                const int f = tid + r * 256;
                const int mi = f >> 3, c4 = (f & 7) << 2;
                const int k = k0 + c4;
                const float* ar = &A[(size_t)(m0 + mi) * K];
                float4 v = make_float4(0.f, 0.f, 0.f, 0.f);
                if (k + 3 < K) v = *(const float4*)&ar[k];
                else {
                    if (k     < K) v.x = ar[k];
                    if (k + 1 < K) v.y = ar[k + 1];
                    if (k + 2 < K) v.z = ar[k + 2];
                }
                As[c4    ][mi] = v.x;
                As[c4 + 1][mi] = v.y;
                As[c4 + 2][mi] = v.z;
                As[c4 + 3][mi] = v.w;
            }
        }
        // ---- stage B tile: Bs[k][n] = W[n][k] ----
        #pragma unroll
        for (int r = 0; r < 2; r++) {
            const int f = tid + r * 256;
            const int ni = f >> 3, kq = (f & 7) << 2;
            const int n = n0 + ni, k = k0 + kq;
            float4 v = make_float4(0.f, 0.f, 0.f, 0.f);
            if (n < N) {
                const float* wrow = &W[(size_t)n * K];
                if (k + 3 < K) v = *(const float4*)&wrow[k];
                else {
                    if (k     < K) v.x = wrow[k];
                    if (k + 1 < K) v.y = wrow[k + 1];
                    if (k + 2 < K) v.z = wrow[k + 2];
                }
            }
            Bs[kq    ][ni] = v.x;
            Bs[kq + 1][ni] = v.y;
            Bs[kq + 2][ni] = v.z;
            Bs[kq + 3][ni] = v.w;
        }
        __syncthreads();

        #pragma unroll
        for (int kk = 0; kk < 32; kk++) {
            const float4 a4 = *(const float4*)&As[kk][ty << 2];
            const float4 b4 = *(const float4*)&Bs[kk][tx << 2];
            const float av[4] = {a4.x, a4.y, a4.z, a4.w};
            const float bv[4] = {b4.x, b4.y, b4.z, b4.w};
            #pragma unroll
            for (int i = 0; i < 4; i++)
                #pragma unroll
                for (int j = 0; j < 4; j++)
                    acc[i][j] += av[i] * bv[j];
        }
        __syncthreads();
    }

    const int nb = n0 + (tx << 2);
    float bv4[4];
    #pragma unroll
    for (int j = 0; j < 4; j++)
        bv4[j] = (nb + j < N) ? bias[nb + j] : 0.f;

    if (!CT) {
        #pragma unroll
        for (int i = 0; i < 4; i++) {
            const int m = m0 + (ty << 2) + i;
            float4 v;
            v.x = acc[i][0] + bv4[0]; v.y = acc[i][1] + bv4[1];
            v.z = acc[i][2] + bv4[2]; v.w = acc[i][3] + bv4[3];
            if (relu) {
                v.x = fmaxf(v.x, 0.f); v.y = fmaxf(v.y, 0.f);
                v.z = fmaxf(v.z, 0.f); v.w = fmaxf(v.w, 0.f);
            }
            if (nb + 3 < N) *(float4*)&C[(size_t)m * N + nb] = v;
            else {
                if (nb     < N) C[(size_t)m * N + nb]     = v.x;
                if (nb + 1 < N) C[(size_t)m * N + nb + 1] = v.y;
                if (nb + 2 < N) C[(size_t)m * N + nb + 2] = v.z;
            }
        }
    } else {
        #pragma unroll
        for (int j = 0; j < 4; j++) {
            if (nb + j < N) {
                float4 v;
                v.x = acc[0][j] + bv4[j]; v.y = acc[1][j] + bv4[j];
                v.z = acc[2][j] + bv4[j]; v.w = acc[3][j] + bv4[j];
                if (relu) {
                    v.x = fmaxf(v.x, 0.f); v.y = fmaxf(v.y, 0.f);
                    v.z = fmaxf(v.z, 0.f); v.w = fmaxf(v.w, 0.f);
                }
                *(float4*)&C[(size_t)(nb + j) * M + m0 + (ty << 2)] = v;
            }
        }
    }
}

// ---------------------------------------------------------------------------
// h_init: transpose gru_state [2][32][256] -> hbuf pingpong slot0 [2][256][32]
// ---------------------------------------------------------------------------
__global__ __launch_bounds__(256) void h_init(
    const float* __restrict__ g0, float* __restrict__ hbuf)
{
    const int i = blockIdx.x * 256 + threadIdx.x;   // 0..16383
    const int net = i >> 13, rest = i & 8191;
    const int bb = rest >> 8, k = rest & 255;
    hbuf[net * 8192 + k * 32 + bb] = g0[i];
}

// ---------------------------------------------------------------------------
// K3: GRU scan (cooperative). 64 blocks = 2 nets x 32 i-slices (8 each).
// giT:  [2][768][4096]  (gate-major, time*batch fastest -> coalesced loads)
// hbuf: [2 pp][2 net][256 i][32 b]  (transposed -> coalesced)
// hidT: [2][256][4096]  relu(h_t), consumed transposed by m1 GEMM (AT mode)
// whh read directly from global (L2-resident, wave-broadcast addresses) to
// take the 192 b128/wave/step weight reads OFF the LDS pipe.
// ---------------------------------------------------------------------------
__global__ __launch_bounds__(256) void gru_scan(
    const float* __restrict__ giT,
    const float* __restrict__ whh_a, const float* __restrict__ whh_c,
    const float* __restrict__ bhh_a, const float* __restrict__ bhh_c,
    const float* __restrict__ done,   // [4096]
    float* __restrict__ hbuf,
    float* __restrict__ hidT,
    float* __restrict__ hT)           // [2][32][256] final h
{
    cg::grid_group gg = cg::this_grid();
    const int bid = blockIdx.x;
    const int net = bid >> 5;
    const int i0  = (bid & 31) << 3;
    const float* whh = net ? whh_c : whh_a;
    const float* bhh = net ? bhh_c : bhh_a;
    const int tid = threadIdx.x;
    const int b  = tid & 31;
    const int il = tid >> 5;
    const int ig = i0 + il;

    __shared__ float Hl[32][260];     // masked h, [b][k]

    const float bh_r = bhh[ig], bh_z = bhh[256 + ig], bh_n = bhh[512 + ig];
    const float* wr = whh + (size_t)ig * 256;
    const float* wz = whh + (size_t)(256 + ig) * 256;
    const float* wn = whh + (size_t)(512 + ig) * 256;
    const float* giR = giT + (size_t)net * 768 * 4096 + (size_t)ig * 4096;
    const float* giZ = giR + (size_t)256 * 4096;
    const float* giN = giR + (size_t)512 * 4096;

    const int sb = (tid & 7) << 2;    // staging batch-quad base
    const int sk = tid >> 3;          // staging k base (0..31), +32 per round

    for (int t = 0; t < NT; t++) {
        const float* hsrc = hbuf + ((size_t)(t & 1) * 2 + net) * 8192;
        float*       hdst = hbuf + ((size_t)((t + 1) & 1) * 2 + net) * 8192;

        // stage masked h: hsrc is [k][b]; float4 over b -> coalesced
        const float4 d4 = *(const float4*)&done[(t << 5) + sb];
        #pragma unroll
        for (int r = 0; r < 8; r++) {
            const int k = sk + (r << 5);
            const float4 hv = *(const float4*)&hsrc[(k << 5) + sb];
            Hl[sb    ][k] = (1.f - d4.x) * hv.x;
            Hl[sb + 1][k] = (1.f - d4.y) * hv.y;
            Hl[sb + 2][k] = (1.f - d4.z) * hv.z;
            Hl[sb + 3][k] = (1.f - d4.w) * hv.w;
        }
        __syncthreads();

        const float gir = giR[(t << 5) + b];
        const float giz = giZ[(t << 5) + b];
        const float gin = giN[(t << 5) + b];

        float ar = 0.f, az = 0.f, an = 0.f;
        const float* hb = &Hl[b][0];
        #pragma unroll 4
        for (int k = 0; k < 256; k += 4) {
            const float4 hv = *(const float4*)(hb + k);
            const float4 w1 = *(const float4*)(wr + k);
            const float4 w2 = *(const float4*)(wz + k);
            const float4 w3 = *(const float4*)(wn + k);
            ar += hv.x * w1.x + hv.y * w1.y + hv.z * w1.z + hv.w * w1.w;
            az += hv.x * w2.x + hv.y * w2.y + hv.z * w2.z + hv.w * w2.w;
            an += hv.x * w3.x + hv.y * w3.y + hv.z * w3.z + hv.w * w3.w;
        }

        const float rr = 1.f / (1.f + expf(-(gir + ar + bh_r)));
        const float zz = 1.f / (1.f + expf(-(giz + az + bh_z)));
        const float nn = tanhf(gin + rr * (an + bh_n));
        const float hm = Hl[b][ig];
        const float hnew = (1.f - zz) * nn + zz * hm;

        hdst[(ig << 5) + b] = hnew;                                     // coalesced
        hidT[((size_t)net * 256 + ig) * 4096 + (t << 5) + b] = fmaxf(hnew, 0.f);
        if (t == NT - 1) hT[net * 8192 + b * 256 + ig] = hnew;

        __threadfence();
        gg.sync();
    }
}

// ---------------------------------------------------------------------------
// K5: heads — actor logits/log_softmax/logp/entropy + critic value.
// m2 arrives TRANSPOSED ([100][4096] per net) -> coalesced lane reads.
// ---------------------------------------------------------------------------
__global__ __launch_bounds__(256) void heads(
    const float* __restrict__ m2Ta, const float* __restrict__ m2Tc,
    const float* __restrict__ aw3, const float* __restrict__ ab3,
    const float* __restrict__ cw3, const float* __restrict__ cb3,
    const int* __restrict__ action,
    float* __restrict__ out)
{
    __shared__ float AW[700], AB[7], CW[100], CB1[1];
    const int tid = threadIdx.x;
    for (int f = tid; f < 700; f += 256) AW[f] = aw3[f];
    if (tid < 7)   AB[tid] = ab3[tid];
    if (tid < 100) CW[tid] = cw3[tid];
    if (tid == 0)  CB1[0] = cb3[0];
    __syncthreads();

    const int r = blockIdx.x * 256 + tid;

    float l[7];
    #pragma unroll
    for (int jj = 0; jj < 7; jj++) l[jj] = AB[jj];
    for (int k = 0; k < 100; k++) {
        const float mv = m2Ta[(size_t)k * TB + r];
        #pragma unroll
        for (int jj = 0; jj < 7; jj++) l[jj] += mv * AW[jj * 100 + k];
    }
    float mx = l[0];
    #pragma unroll
    for (int jj = 1; jj < 7; jj++) mx = fmaxf(mx, l[jj]);
    float se = 0.f;
    #pragma unroll
    for (int jj = 0; jj < 7; jj++) se += expf(l[jj] - mx);
    const float lse = logf(se);
    const int a = action[r];
    float ent = 0.f, lp_a = 0.f;
    #pragma unroll
    for (int jj = 0; jj < 7; jj++) {
        const float lp = l[jj] - mx - lse;
        ent -= expf(lp) * lp;
        if (jj == a) lp_a = lp;
    }

    float v = CB1[0];
    for (int k = 0; k < 100; k++) v += m2Tc[(size_t)k * TB + r] * CW[k];

    out[r]          = (float)a;
    out[TB + r]     = lp_a;
    out[2 * TB + r] = ent;
    out[3 * TB + r] = v;
}

// ---------------------------------------------------------------------------
extern "C" void kernel_launch(void* const* d_in, const int* in_sizes, int n_in,
                              void* d_out, int out_size, void* d_ws, size_t ws_size,
                              hipStream_t stream)
{
    const float* x     = (const float*)d_in[0];
    const float* gru0  = (const float*)d_in[1];
    const float* done  = (const float*)d_in[2];
    const int*   act   = (const int*)d_in[3];
    #define AIN(i) ((const float*)d_in[4 + (i)])
    #define CIN(i) ((const float*)d_in[20 + (i)])
    // per-net order: c1w,c1b,c2w,c2b,fw,fb,wih,whh,bih,bhh,h1w,h1b,h2w,h2b,h3w,h3b

    // Workspace aliasing (same 12,713,984-float footprint as previous round):
    // region1 (10,616,832 f): y2 during conv/FC phase; then giT+m1+m2T+hbuf+hT.
    // region2 ( 2,097,152 f): feats during FC/gi phase; then hidT.
    float* ws = (float*)d_ws;
    float* region1 = ws;
    float* region2 = ws + (size_t)TB * 2592;

    float* y2   = region1;                         // [4096][2592]
    float* giT  = region1;                         // [2][768][4096] (after y2 dead)
    float* m1   = giT + (size_t)2 * 768 * 4096;    // [2][4096][200]
    float* m2T  = m1  + (size_t)2 * TB * 200;      // [2][100][4096]
    float* hbuf = m2T + (size_t)2 * TB * 100;      // [2 pp][2 net][256][32]
    float* hTb  = hbuf + 2 * 2 * 256 * 32;         // [2][32][256]

    float* feats = region2;                        // [2][4096][256]
    float* hidT  = region2;                        // [2][256][4096] (after feats dead)

    float* feats_c = feats + (size_t)TB * 256;
    float* giT_c   = giT  + (size_t)768 * 4096;
    float* m1_c    = m1   + (size_t)TB * 200;
    float* m2T_c   = m2T  + (size_t)TB * 100;
    float* hidT_c  = hidT + (size_t)256 * 4096;

    // ---- actor CNN + FC ----
    conv_front<<<TB, 256, 0, stream>>>(x, AIN(0), AIN(1), AIN(2), AIN(3), y2);
    gemm64<<<dim3(64, 4), 256, 0, stream>>>(y2, AIN(4), AIN(5), feats,
                                            TB, 256, 2592, 1, 0, 0);
    // ---- critic CNN + FC (reuse y2) ----
    conv_front<<<TB, 256, 0, stream>>>(x, CIN(0), CIN(1), CIN(2), CIN(3), y2);
    gemm64<<<dim3(64, 4), 256, 0, stream>>>(y2, CIN(4), CIN(5), feats_c,
                                            TB, 256, 2592, 1, 0, 0);

    // ---- gi = feats @ wih^T + bih, written TRANSPOSED; y2 dead now ----
    gemm64<<<dim3(64, 12), 256, 0, stream>>>(feats, AIN(6), AIN(8), giT,
                                             TB, 768, 256, 0, 0, 1);
    gemm64<<<dim3(64, 12), 256, 0, stream>>>(feats_c, CIN(6), CIN(8), giT_c,
                                             TB, 768, 256, 0, 0, 1);

    // ---- init h (transposed pingpong slot 0), cooperative scan ----
    h_init<<<64, 256, 0, stream>>>(gru0, hbuf);
    {
        const float* gi_p = giT;
        const float* whh_a = AIN(7); const float* whh_c = CIN(7);
        const float* bhh_a = AIN(9); const float* bhh_c = CIN(9);
        const float* done_p = done;
        float* hbuf_p = hbuf; float* hidT_p = hidT; float* hT_p = hTb;
        void* args[] = {(void*)&gi_p, (void*)&whh_a, (void*)&whh_c,
                        (void*)&bhh_a, (void*)&bhh_c, (void*)&done_p,
                        (void*)&hbuf_p, (void*)&hidT_p, (void*)&hT_p};
        hipLaunchCooperativeKernel((void*)gru_scan, dim3(64), dim3(256),
                                   args, 0, stream);
    }

    // ---- MLPs: m1 reads hidT via AT mode; m2 written transposed for heads ----
    gemm64<<<dim3(64, 4), 256, 0, stream>>>(hidT, AIN(10), AIN(11), m1,
                                            TB, 200, 256, 1, 1, 0);
    gemm64<<<dim3(64, 4), 256, 0, stream>>>(hidT_c, CIN(10), CIN(11), m1_c,
                                            TB, 200, 256, 1, 1, 0);
    gemm64<<<dim3(64, 2), 256, 0, stream>>>(m1, AIN(12), AIN(13), m2T,
                                            TB, 100, 200, 1, 0, 1);
    gemm64<<<dim3(64, 2), 256, 0, stream>>>(m1_c, CIN(12), CIN(13), m2T_c,
                                            TB, 100, 200, 1, 0, 1);

    // ---- heads + hT ----
    float* out = (float*)d_out;
    heads<<<TB / 256, 256, 0, stream>>>(m2T, m2T_c, AIN(14), AIN(15),
                                        CIN(14), CIN(15), act, out);
    hipMemcpyAsync(out + 4 * TB, hTb, (size_t)2 * NB * H * sizeof(float),
                   hipMemcpyDeviceToDevice, stream);
}

// Round 2
// 3817.741 us; speedup vs baseline: 2.4514x; 1.5614x over previous
//
#include <hip/hip_runtime.h>
#include <hip/hip_bf16.h>

#define TB 4096   // T*B
#define NB 32     // B
#define NT 128    // T
#define H 256

// ---------------------------------------------------------------------------
// K1: conv1(8x8 s4) + relu + conv2(4x4 s2) + relu, fused per (img) block.
// x: [4096][4][84][84], out y2: [4096][2592] (channel-major flatten).
// (unchanged)
// ---------------------------------------------------------------------------
__global__ __launch_bounds__(256) void conv_front(
    const float* __restrict__ x,
    const float* __restrict__ w1, const float* __restrict__ b1,
    const float* __restrict__ w2, const float* __restrict__ b2,
    float* __restrict__ y2)
{
    __shared__ float WBUF[8192];
    __shared__ float S1[6400];
    __shared__ float B1s[16], B2s[32];

    const int img = blockIdx.x;
    const int tid = threadIdx.x;

    for (int f = tid; f < 4096; f += 256) WBUF[f] = w1[f];
    if (tid < 16) B1s[tid] = b1[tid];
    if (tid < 32) B2s[tid] = b2[tid];
    __syncthreads();

    const float* xi = x + (size_t)img * 4 * 84 * 84;

    for (int pos = tid; pos < 400; pos += 256) {
        const int oy = pos / 20, ox = pos % 20;
        const int iy = oy * 4, ix = ox * 4;
        float acc[16];
        #pragma unroll
        for (int c = 0; c < 16; c++) acc[c] = B1s[c];
        for (int ci = 0; ci < 4; ci++) {
            #pragma unroll
            for (int ky = 0; ky < 8; ky++) {
                const float* xr = xi + ci * 7056 + (iy + ky) * 84 + ix;
                const float4 x0 = *(const float4*)(xr);
                const float4 x1 = *(const float4*)(xr + 4);
                #pragma unroll
                for (int co = 0; co < 16; co++) {
                    const float* wr = &WBUF[((co * 4 + ci) * 8 + ky) * 8];
                    const float4 wa = *(const float4*)(wr);
                    const float4 wb = *(const float4*)(wr + 4);
                    acc[co] += x0.x * wa.x + x0.y * wa.y + x0.z * wa.z + x0.w * wa.w
                             + x1.x * wb.x + x1.y * wb.y + x1.z * wb.z + x1.w * wb.w;
                }
            }
        }
        #pragma unroll
        for (int co = 0; co < 16; co++)
            S1[co * 400 + pos] = fmaxf(acc[co], 0.f);
    }
    __syncthreads();

    for (int f = tid; f < 8192; f += 256) WBUF[f] = w2[f];
    __syncthreads();

    if (tid < 243) {
        const int cgI = tid / 81, pos = tid % 81;
        const int co0 = cgI * 11;
        const int ncg = (cgI == 2) ? 10 : 11;
        const int oy = pos / 9, ox = pos % 9;
        const int iy = oy * 2, ix = ox * 2;
        float acc[11];
        #pragma unroll
        for (int c = 0; c < 11; c++) acc[c] = (c < ncg) ? B2s[co0 + c] : 0.f;
        for (int ci = 0; ci < 16; ci++) {
            #pragma unroll
            for (int ky = 0; ky < 4; ky++) {
                const float* sr = &S1[ci * 400 + (iy + ky) * 20 + ix];
                const float2 f0 = *(const float2*)(sr);
                const float2 f1 = *(const float2*)(sr + 2);
                for (int c = 0; c < ncg; c++) {
                    const float4 w4 = *(const float4*)&WBUF[((co0 + c) * 16 + ci) * 16 + ky * 4];
                    acc[c] += f0.x * w4.x + f0.y * w4.y + f1.x * w4.z + f1.y * w4.w;
                }
            }
        }
        float* yo = y2 + (size_t)img * 2592;
        for (int c = 0; c < ncg; c++)
            yo[(co0 + c) * 81 + pos] = fmaxf(acc[c], 0.f);
    }
}

// ---------------------------------------------------------------------------
// K2: register-tiled GEMM.  C[M,N] = act(A[M,K] @ W[N,K]^T + bias).
// Tile 64x64, BK=32, 256 threads, 4x4 accs/thread.
// AT: A stored transposed [K][M].  CT: C written transposed [N][M].
// (unchanged)
// ---------------------------------------------------------------------------
__global__ __launch_bounds__(256) void gemm64(
    const float* __restrict__ A, const float* __restrict__ W,
    const float* __restrict__ bias, float* __restrict__ C,
    int M, int N, int K, int relu, int AT, int CT)
{
    __shared__ float As[32][68];   // [k][m]
    __shared__ float Bs[32][68];   // [k][n]
    const int tid = threadIdx.x;
    const int m0 = blockIdx.x * 64;
    const int n0 = blockIdx.y * 64;
    const int tx = tid & 15, ty = tid >> 4;

    float acc[4][4];
    #pragma unroll
    for (int i = 0; i < 4; i++)
        #pragma unroll
        for (int j = 0; j < 4; j++) acc[i][j] = 0.f;

    for (int k0 = 0; k0 < K; k0 += 32) {
        if (AT) {
            #pragma unroll
            for (int r = 0; r < 2; r++) {
                const int f = tid + r * 256;
                const int kk = f >> 4, m4 = (f & 15) << 2;
                float4 v = make_float4(0.f, 0.f, 0.f, 0.f);
                if (k0 + kk < K) v = *(const float4*)&A[(size_t)(k0 + kk) * M + m0 + m4];
                *(float4*)&As[kk][m4] = v;
            }
        } else {
            #pragma unroll
            for (int r = 0; r < 2; r++) {
                const int f = tid + r * 256;
                const int mi = f >> 3, c4 = (f & 7) << 2;
                const int k = k0 + c4;
                const float* ar = &A[(size_t)(m0 + mi) * K];
                float4 v = make_float4(0.f, 0.f, 0.f, 0.f);
                if (k + 3 < K) v = *(const float4*)&ar[k];
                else {
                    if (k     < K) v.x = ar[k];
                    if (k + 1 < K) v.y = ar[k + 1];
                    if (k + 2 < K) v.z = ar[k + 2];
                }
                As[c4    ][mi] = v.x;
                As[c4 + 1][mi] = v.y;
                As[c4 + 2][mi] = v.z;
                As[c4 + 3][mi] = v.w;
            }
        }
        #pragma unroll
        for (int r = 0; r < 2; r++) {
            const int f = tid + r * 256;
            const int ni = f >> 3, kq = (f & 7) << 2;
            const int n = n0 + ni, k = k0 + kq;
            float4 v = make_float4(0.f, 0.f, 0.f, 0.f);
            if (n < N) {
                const float* wrow = &W[(size_t)n * K];
                if (k + 3 < K) v = *(const float4*)&wrow[k];
                else {
                    if (k     < K) v.x = wrow[k];
                    if (k + 1 < K) v.y = wrow[k + 1];
                    if (k + 2 < K) v.z = wrow[k + 2];
                }
            }
            Bs[kq    ][ni] = v.x;
            Bs[kq + 1][ni] = v.y;
            Bs[kq + 2][ni] = v.z;
            Bs[kq + 3][ni] = v.w;
        }
        __syncthreads();

        #pragma unroll
        for (int kk = 0; kk < 32; kk++) {
            const float4 a4 = *(const float4*)&As[kk][ty << 2];
            const float4 b4 = *(const float4*)&Bs[kk][tx << 2];
            const float av[4] = {a4.x, a4.y, a4.z, a4.w};
            const float bv[4] = {b4.x, b4.y, b4.z, b4.w};
            #pragma unroll
            for (int i = 0; i < 4; i++)
                #pragma unroll
                for (int j = 0; j < 4; j++)
                    acc[i][j] += av[i] * bv[j];
        }
        __syncthreads();
    }

    const int nb = n0 + (tx << 2);
    float bv4[4];
    #pragma unroll
    for (int j = 0; j < 4; j++)
        bv4[j] = (nb + j < N) ? bias[nb + j] : 0.f;

    if (!CT) {
        #pragma unroll
        for (int i = 0; i < 4; i++) {
            const int m = m0 + (ty << 2) + i;
            float4 v;
            v.x = acc[i][0] + bv4[0]; v.y = acc[i][1] + bv4[1];
            v.z = acc[i][2] + bv4[2]; v.w = acc[i][3] + bv4[3];
            if (relu) {
                v.x = fmaxf(v.x, 0.f); v.y = fmaxf(v.y, 0.f);
                v.z = fmaxf(v.z, 0.f); v.w = fmaxf(v.w, 0.f);
            }
            if (nb + 3 < N) *(float4*)&C[(size_t)m * N + nb] = v;
            else {
                if (nb     < N) C[(size_t)m * N + nb]     = v.x;
                if (nb + 1 < N) C[(size_t)m * N + nb + 1] = v.y;
                if (nb + 2 < N) C[(size_t)m * N + nb + 2] = v.z;
            }
        }
    } else {
        #pragma unroll
        for (int j = 0; j < 4; j++) {
            if (nb + j < N) {
                float4 v;
                v.x = acc[0][j] + bv4[j]; v.y = acc[1][j] + bv4[j];
                v.z = acc[2][j] + bv4[j]; v.w = acc[3][j] + bv4[j];
                if (relu) {
                    v.x = fmaxf(v.x, 0.f); v.y = fmaxf(v.y, 0.f);
                    v.z = fmaxf(v.z, 0.f); v.w = fmaxf(v.w, 0.f);
                }
                *(float4*)&C[(size_t)(nb + j) * M + m0 + (ty << 2)] = v;
            }
        }
    }
}

// ---------------------------------------------------------------------------
// pack_whh: whh [768][256] -> wp4 float4-packed [64 k4][768 j]
// wp4[k4*768 + j] = whh[j][4k4 .. 4k4+3]; coalesced stores, one-time cost.
// ---------------------------------------------------------------------------
__global__ __launch_bounds__(256) void pack_whh(
    const float* __restrict__ whh, float* __restrict__ wp4)
{
    const int idx = blockIdx.x * 256 + threadIdx.x;   // 0..49151
    const int j = idx % 768, k4 = idx / 768;
    const float4 v = *(const float4*)&whh[(size_t)j * 256 + k4 * 4];
    *(float4*)&wp4[(size_t)(k4 * 768 + j) * 4] = v;
}

// ---------------------------------------------------------------------------
// K3: GRU scan, NO grid sync.  64 blocks = 2 nets x 32 batch rows; each block
// owns the full 768-gate recurrence for its row.  h[256] lives in LDS; the
// only per-step sync is __syncthreads.  Thread j computes gate-row j's dot
// over h (LDS broadcast reads); weights stream from L2 via the coalesced
// wp4 [k4][j] float4 layout (1.5 MB both nets -> L2-resident per XCD).
// done in {0,1} exactly, so (1-d) factors out of the dot bit-exactly.
// gi:  [2][4096][768] row-major (bih already added)
// hid: [2][4096][256] row-major relu(h_t)
// hT written directly to out+4*TB: [2][32][256]
// ---------------------------------------------------------------------------
__global__ __launch_bounds__(768) void gru_scan2(
    const float* __restrict__ gi,
    const float* __restrict__ wp4_a, const float* __restrict__ wp4_c,
    const float* __restrict__ bhh_a, const float* __restrict__ bhh_c,
    const float* __restrict__ done,   // [4096]
    const float* __restrict__ h0,     // [2][32][256]
    float* __restrict__ hid,
    float* __restrict__ hT)
{
    const int net = blockIdx.x >> 5;
    const int b   = blockIdx.x & 31;
    const int tid = threadIdx.x;      // 0..767 = gate-row j

    __shared__ float hs[256];         // current h
    __shared__ float sb[768];         // per-gate pre-activations

    const float4* wp = (const float4*)(net ? wp4_c : wp4_a);
    const float*  bhh = net ? bhh_c : bhh_a;
    const float   bh  = bhh[tid];
    const float*  gib = gi + (size_t)net * TB * 768;

    if (tid < 256) hs[tid] = h0[net * 8192 + b * 256 + tid];
    __syncthreads();

    for (int t = 0; t < NT; t++) {
        const int   row = t * 32 + b;
        const float d1  = 1.f - done[row];

        // phase 1: all 768 threads -> one dot over h
        float acc = 0.f;
        #pragma unroll 8
        for (int k4 = 0; k4 < 64; k4++) {
            const float4 w  = wp[k4 * 768 + tid];
            const float4 h4 = *(const float4*)&hs[k4 * 4];
            acc += w.x * h4.x + w.y * h4.y + w.z * h4.z + w.w * h4.w;
        }
        float s = d1 * acc + bh;
        if (tid < 512) s += gib[(size_t)row * 768 + tid];   // r,z add gi here
        sb[tid] = s;
        __syncthreads();

        // phase 2: threads 0..255 combine gates -> h_new
        if (tid < 256) {
            const float r   = 1.f / (1.f + expf(-sb[tid]));
            const float z   = 1.f / (1.f + expf(-sb[256 + tid]));
            const float gin = gib[(size_t)row * 768 + 512 + tid];
            const float n   = tanhf(gin + r * sb[512 + tid]);
            const float hm  = d1 * hs[tid];
            const float hnew = (1.f - z) * n + z * hm;
            hs[tid] = hnew;
            hid[((size_t)net * TB + row) * 256 + tid] = fmaxf(hnew, 0.f);
            if (t == NT - 1) hT[net * 8192 + b * 256 + tid] = hnew;
        }
        __syncthreads();
    }
}

// ---------------------------------------------------------------------------
// K5: heads — m2 arrives TRANSPOSED ([100][4096] per net).  (unchanged)
// ---------------------------------------------------------------------------
__global__ __launch_bounds__(256) void heads(
    const float* __restrict__ m2Ta, const float* __restrict__ m2Tc,
    const float* __restrict__ aw3, const float* __restrict__ ab3,
    const float* __restrict__ cw3, const float* __restrict__ cb3,
    const int* __restrict__ action,
    float* __restrict__ out)
{
    __shared__ float AW[700], AB[7], CW[100], CB1[1];
    const int tid = threadIdx.x;
    for (int f = tid; f < 700; f += 256) AW[f] = aw3[f];
    if (tid < 7)   AB[tid] = ab3[tid];
    if (tid < 100) CW[tid] = cw3[tid];
    if (tid == 0)  CB1[0] = cb3[0];
    __syncthreads();

    const int r = blockIdx.x * 256 + tid;

    float l[7];
    #pragma unroll
    for (int jj = 0; jj < 7; jj++) l[jj] = AB[jj];
    for (int k = 0; k < 100; k++) {
        const float mv = m2Ta[(size_t)k * TB + r];
        #pragma unroll
        for (int jj = 0; jj < 7; jj++) l[jj] += mv * AW[jj * 100 + k];
    }
    float mx = l[0];
    #pragma unroll
    for (int jj = 1; jj < 7; jj++) mx = fmaxf(mx, l[jj]);
    float se = 0.f;
    #pragma unroll
    for (int jj = 0; jj < 7; jj++) se += expf(l[jj] - mx);
    const float lse = logf(se);
    const int a = action[r];
    float ent = 0.f, lp_a = 0.f;
    #pragma unroll
    for (int jj = 0; jj < 7; jj++) {
        const float lp = l[jj] - mx - lse;
        ent -= expf(lp) * lp;
        if (jj == a) lp_a = lp;
    }

    float v = CB1[0];
    for (int k = 0; k < 100; k++) v += m2Tc[(size_t)k * TB + r] * CW[k];

    out[r]          = (float)a;
    out[TB + r]     = lp_a;
    out[2 * TB + r] = ent;
    out[3 * TB + r] = v;
}

// ---------------------------------------------------------------------------
extern "C" void kernel_launch(void* const* d_in, const int* in_sizes, int n_in,
                              void* d_out, int out_size, void* d_ws, size_t ws_size,
                              hipStream_t stream)
{
    const float* x     = (const float*)d_in[0];
    const float* gru0  = (const float*)d_in[1];
    const float* done  = (const float*)d_in[2];
    const int*   act   = (const int*)d_in[3];
    #define AIN(i) ((const float*)d_in[4 + (i)])
    #define CIN(i) ((const float*)d_in[20 + (i)])
    // per-net order: c1w,c1b,c2w,c2b,fw,fb,wih,whh,bih,bhh,h1w,h1b,h2w,h2b,h3w,h3b

    // Workspace (12,713,984 floats, same as before):
    // region1 (10,616,832 f): y2 during conv/FC phase; then gi+m1+m2T+wp4.
    // region2 ( 2,097,152 f): feats during FC/gi phase; then hid.
    float* ws = (float*)d_ws;
    float* region1 = ws;
    float* region2 = ws + (size_t)TB * 2592;

    float* y2    = region1;                         // [4096][2592]
    float* gi    = region1;                         // [2][4096][768] (after y2 dead)
    float* m1    = gi  + (size_t)2 * TB * 768;      // [2][4096][200]
    float* m2T   = m1  + (size_t)2 * TB * 200;      // [2][100][4096]
    float* wp4_a = m2T + (size_t)2 * TB * 100;      // [64][768][4] packed whh (actor)
    float* wp4_c = wp4_a + (size_t)64 * 768 * 4;    // same (critic)

    float* feats = region2;                         // [2][4096][256]
    float* hid   = region2;                         // [2][4096][256] (after feats dead)

    float* feats_c = feats + (size_t)TB * 256;
    float* gi_c    = gi    + (size_t)TB * 768;
    float* m1_c    = m1    + (size_t)TB * 200;
    float* m2T_c   = m2T   + (size_t)TB * 100;
    float* hid_c   = hid   + (size_t)TB * 256;

    // ---- actor CNN + FC ----
    conv_front<<<TB, 256, 0, stream>>>(x, AIN(0), AIN(1), AIN(2), AIN(3), y2);
    gemm64<<<dim3(64, 4), 256, 0, stream>>>(y2, AIN(4), AIN(5), feats,
                                            TB, 256, 2592, 1, 0, 0);
    // ---- critic CNN + FC (reuse y2) ----
    conv_front<<<TB, 256, 0, stream>>>(x, CIN(0), CIN(1), CIN(2), CIN(3), y2);
    gemm64<<<dim3(64, 4), 256, 0, stream>>>(y2, CIN(4), CIN(5), feats_c,
                                            TB, 256, 2592, 1, 0, 0);

    // ---- y2 dead: pack whh for the scan; gi row-major (bih added) ----
    pack_whh<<<192, 256, 0, stream>>>(AIN(7), wp4_a);
    pack_whh<<<192, 256, 0, stream>>>(CIN(7), wp4_c);
    gemm64<<<dim3(64, 12), 256, 0, stream>>>(feats, AIN(6), AIN(8), gi,
                                             TB, 768, 256, 0, 0, 0);
    gemm64<<<dim3(64, 12), 256, 0, stream>>>(feats_c, CIN(6), CIN(8), gi_c,
                                             TB, 768, 256, 0, 0, 0);

    // ---- GRU scan: 64 independent blocks, no grid sync ----
    float* out = (float*)d_out;
    gru_scan2<<<64, 768, 0, stream>>>(gi, wp4_a, wp4_c, AIN(9), CIN(9),
                                      done, gru0, hid, out + 4 * TB);

    // ---- MLPs: m1 reads hid row-major; m2 written transposed for heads ----
    gemm64<<<dim3(64, 4), 256, 0, stream>>>(hid, AIN(10), AIN(11), m1,
                                            TB, 200, 256, 1, 0, 0);
    gemm64<<<dim3(64, 4), 256, 0, stream>>>(hid_c, CIN(10), CIN(11), m1_c,
                                            TB, 200, 256, 1, 0, 0);
    gemm64<<<dim3(64, 2), 256, 0, stream>>>(m1, AIN(12), AIN(13), m2T,
                                            TB, 100, 200, 1, 0, 1);
    gemm64<<<dim3(64, 2), 256, 0, stream>>>(m1_c, CIN(12), CIN(13), m2T_c,
                                            TB, 100, 200, 1, 0, 1);

    // ---- heads ----
    heads<<<TB / 256, 256, 0, stream>>>(m2T, m2T_c, AIN(14), AIN(15),
                                        CIN(14), CIN(15), act, out);
}

// Round 3
// 2726.851 us; speedup vs baseline: 3.4321x; 1.4001x over previous
//
#include <hip/hip_runtime.h>
#include <hip/hip_bf16.h>

#define TB 4096   // T*B
#define NB 32     // B
#define NT 128    // T
#define H 256

// ---------------------------------------------------------------------------
// K1: conv1(8x8 s4)+relu -> S1(LDS) -> conv2(4x4 s2)+relu, one image/block.
// Weights live in REGISTERS (wave-uniform scalar loads via readfirstlane),
// reused across all positions; x streamed from global (L1-resident window).
// Wave w owns co-slice: conv1 -> co {4w..4w+3}, conv2 -> co {8w..8w+7}.
// Lane l owns positions {l, l+64, ...}.
// y2: [4096][2592] channel-major flatten (co*81 + pos), as before.
// ---------------------------------------------------------------------------
__global__ __launch_bounds__(256) void conv_front2(
    const float* __restrict__ x,
    const float* __restrict__ w1, const float* __restrict__ b1,
    const float* __restrict__ w2, const float* __restrict__ b2,
    float* __restrict__ y2)
{
    __shared__ float S1[16 * 400];        // conv1 out [16][400], 25.6 KB

    const int img = blockIdx.x;
    const int tid = threadIdx.x;
    const int ws  = __builtin_amdgcn_readfirstlane(tid >> 6);  // wave id (uniform)
    const int l   = tid & 63;

    const float* xi = x + (size_t)img * 4 * 84 * 84;

    // ---------------- conv1 ----------------
    // positions: slots p=0..5 full (pos = l+64p), slot 6 only lanes l<16.
    int iyv[6], ixv[6];
    #pragma unroll
    for (int p = 0; p < 6; p++) {
        const int pos = l + (p << 6);
        iyv[p] = (pos / 20) * 4;
        ixv[p] = (pos % 20) * 4;
    }
    const int pos6 = l + 384;
    const int iy6 = (pos6 / 20) * 4, ix6 = (pos6 % 20) * 4;
    const bool t6 = (l < 16);

    float acc[4][7];
    #pragma unroll
    for (int c = 0; c < 4; c++) {
        const float bv = b1[4 * ws + c];
        #pragma unroll
        for (int p = 0; p < 7; p++) acc[c][p] = bv;
    }

    for (int ci = 0; ci < 4; ci++) {
        #pragma unroll 1
        for (int ky = 0; ky < 8; ky++) {
            // weights for this (ci,ky): 4 co x 8 kx — wave-uniform scalar loads
            float4 wa[4], wb[4];
            #pragma unroll
            for (int c = 0; c < 4; c++) {
                const float* wr = w1 + (((4 * ws + c) * 4 + ci) * 8 + ky) * 8;
                wa[c] = *(const float4*)wr;
                wb[c] = *(const float4*)(wr + 4);
            }
            const float* xrow = xi + ci * 7056 + ky * 84;
            #pragma unroll
            for (int p = 0; p < 6; p++) {
                const float* xr = xrow + iyv[p] * 84 + ixv[p];
                const float4 x0 = *(const float4*)xr;
                const float4 x1 = *(const float4*)(xr + 4);
                #pragma unroll
                for (int c = 0; c < 4; c++)
                    acc[c][p] += x0.x * wa[c].x + x0.y * wa[c].y + x0.z * wa[c].z + x0.w * wa[c].w
                               + x1.x * wb[c].x + x1.y * wb[c].y + x1.z * wb[c].z + x1.w * wb[c].w;
            }
            if (t6) {
                const float* xr = xrow + iy6 * 84 + ix6;
                const float4 x0 = *(const float4*)xr;
                const float4 x1 = *(const float4*)(xr + 4);
                #pragma unroll
                for (int c = 0; c < 4; c++)
                    acc[c][6] += x0.x * wa[c].x + x0.y * wa[c].y + x0.z * wa[c].z + x0.w * wa[c].w
                               + x1.x * wb[c].x + x1.y * wb[c].y + x1.z * wb[c].z + x1.w * wb[c].w;
            }
        }
    }
    #pragma unroll
    for (int c = 0; c < 4; c++) {
        #pragma unroll
        for (int p = 0; p < 6; p++)
            S1[(4 * ws + c) * 400 + l + (p << 6)] = fmaxf(acc[c][p], 0.f);
        if (t6)
            S1[(4 * ws + c) * 400 + pos6] = fmaxf(acc[c][6], 0.f);
    }
    __syncthreads();

    // ---------------- conv2 ----------------
    // 81 positions: slot0 = l (all lanes), slot1 = l+64 (lanes l<17).
    const int oy0 = l / 9, ox0 = l % 9;
    const int p1 = l + 64;
    const bool t1 = (p1 < 81);
    const int oy1 = p1 / 9, ox1 = p1 % 9;

    float a2[8][2];
    #pragma unroll
    for (int c = 0; c < 8; c++) {
        const float bv = b2[8 * ws + c];
        a2[c][0] = bv; a2[c][1] = bv;
    }

    for (int ci = 0; ci < 16; ci++) {
        #pragma unroll 1
        for (int ky = 0; ky < 4; ky++) {
            float4 wv[8];
            #pragma unroll
            for (int c = 0; c < 8; c++)
                wv[c] = *(const float4*)(w2 + ((((8 * ws + c) * 16 + ci) * 16) + ky * 4));
            {
                const float* sr = &S1[ci * 400 + (oy0 * 2 + ky) * 20 + ox0 * 2];
                const float2 f0 = *(const float2*)sr;
                const float2 f1 = *(const float2*)(sr + 2);
                #pragma unroll
                for (int c = 0; c < 8; c++)
                    a2[c][0] += f0.x * wv[c].x + f0.y * wv[c].y + f1.x * wv[c].z + f1.y * wv[c].w;
            }
            if (t1) {
                const float* sr = &S1[ci * 400 + (oy1 * 2 + ky) * 20 + ox1 * 2];
                const float2 f0 = *(const float2*)sr;
                const float2 f1 = *(const float2*)(sr + 2);
                #pragma unroll
                for (int c = 0; c < 8; c++)
                    a2[c][1] += f0.x * wv[c].x + f0.y * wv[c].y + f1.x * wv[c].z + f1.y * wv[c].w;
            }
        }
    }
    float* yo = y2 + (size_t)img * 2592;
    #pragma unroll
    for (int c = 0; c < 8; c++) {
        yo[(8 * ws + c) * 81 + l] = fmaxf(a2[c][0], 0.f);
        if (t1) yo[(8 * ws + c) * 81 + p1] = fmaxf(a2[c][1], 0.f);
    }
}

// ---------------------------------------------------------------------------
// K2: register-tiled GEMM.  C[M,N] = act(A[M,K] @ W[N,K]^T + bias).
// Tile 64x64, BK=32, 256 threads, 4x4 accs/thread.
// AT: A stored transposed [K][M].  CT: C written transposed [N][M].
// (unchanged)
// ---------------------------------------------------------------------------
__global__ __launch_bounds__(256) void gemm64(
    const float* __restrict__ A, const float* __restrict__ W,
    const float* __restrict__ bias, float* __restrict__ C,
    int M, int N, int K, int relu, int AT, int CT)
{
    __shared__ float As[32][68];   // [k][m]
    __shared__ float Bs[32][68];   // [k][n]
    const int tid = threadIdx.x;
    const int m0 = blockIdx.x * 64;
    const int n0 = blockIdx.y * 64;
    const int tx = tid & 15, ty = tid >> 4;

    float acc[4][4];
    #pragma unroll
    for (int i = 0; i < 4; i++)
        #pragma unroll
        for (int j = 0; j < 4; j++) acc[i][j] = 0.f;

    for (int k0 = 0; k0 < K; k0 += 32) {
        if (AT) {
            #pragma unroll
            for (int r = 0; r < 2; r++) {
                const int f = tid + r * 256;
                const int kk = f >> 4, m4 = (f & 15) << 2;
                float4 v = make_float4(0.f, 0.f, 0.f, 0.f);
                if (k0 + kk < K) v = *(const float4*)&A[(size_t)(k0 + kk) * M + m0 + m4];
                *(float4*)&As[kk][m4] = v;
            }
        } else {
            #pragma unroll
            for (int r = 0; r < 2; r++) {
                const int f = tid + r * 256;
                const int mi = f >> 3, c4 = (f & 7) << 2;
                const int k = k0 + c4;
                const float* ar = &A[(size_t)(m0 + mi) * K];
                float4 v = make_float4(0.f, 0.f, 0.f, 0.f);
                if (k + 3 < K) v = *(const float4*)&ar[k];
                else {
                    if (k     < K) v.x = ar[k];
                    if (k + 1 < K) v.y = ar[k + 1];
                    if (k + 2 < K) v.z = ar[k + 2];
                }
                As[c4    ][mi] = v.x;
                As[c4 + 1][mi] = v.y;
                As[c4 + 2][mi] = v.z;
                As[c4 + 3][mi] = v.w;
            }
        }
        #pragma unroll
        for (int r = 0; r < 2; r++) {
            const int f = tid + r * 256;
            const int ni = f >> 3, kq = (f & 7) << 2;
            const int n = n0 + ni, k = k0 + kq;
            float4 v = make_float4(0.f, 0.f, 0.f, 0.f);
            if (n < N) {
                const float* wrow = &W[(size_t)n * K];
                if (k + 3 < K) v = *(const float4*)&wrow[k];
                else {
                    if (k     < K) v.x = wrow[k];
                    if (k + 1 < K) v.y = wrow[k + 1];
                    if (k + 2 < K) v.z = wrow[k + 2];
                }
            }
            Bs[kq    ][ni] = v.x;
            Bs[kq + 1][ni] = v.y;
            Bs[kq + 2][ni] = v.z;
            Bs[kq + 3][ni] = v.w;
        }
        __syncthreads();

        #pragma unroll
        for (int kk = 0; kk < 32; kk++) {
            const float4 a4 = *(const float4*)&As[kk][ty << 2];
            const float4 b4 = *(const float4*)&Bs[kk][tx << 2];
            const float av[4] = {a4.x, a4.y, a4.z, a4.w};
            const float bv[4] = {b4.x, b4.y, b4.z, b4.w};
            #pragma unroll
            for (int i = 0; i < 4; i++)
                #pragma unroll
                for (int j = 0; j < 4; j++)
                    acc[i][j] += av[i] * bv[j];
        }
        __syncthreads();
    }

    const int nb = n0 + (tx << 2);
    float bv4[4];
    #pragma unroll
    for (int j = 0; j < 4; j++)
        bv4[j] = (nb + j < N) ? bias[nb + j] : 0.f;

    if (!CT) {
        #pragma unroll
        for (int i = 0; i < 4; i++) {
            const int m = m0 + (ty << 2) + i;
            float4 v;
            v.x = acc[i][0] + bv4[0]; v.y = acc[i][1] + bv4[1];
            v.z = acc[i][2] + bv4[2]; v.w = acc[i][3] + bv4[3];
            if (relu) {
                v.x = fmaxf(v.x, 0.f); v.y = fmaxf(v.y, 0.f);
                v.z = fmaxf(v.z, 0.f); v.w = fmaxf(v.w, 0.f);
            }
            if (nb + 3 < N) *(float4*)&C[(size_t)m * N + nb] = v;
            else {
                if (nb     < N) C[(size_t)m * N + nb]     = v.x;
                if (nb + 1 < N) C[(size_t)m * N + nb + 1] = v.y;
                if (nb + 2 < N) C[(size_t)m * N + nb + 2] = v.z;
            }
        }
    } else {
        #pragma unroll
        for (int j = 0; j < 4; j++) {
            if (nb + j < N) {
                float4 v;
                v.x = acc[0][j] + bv4[j]; v.y = acc[1][j] + bv4[j];
                v.z = acc[2][j] + bv4[j]; v.w = acc[3][j] + bv4[j];
                if (relu) {
                    v.x = fmaxf(v.x, 0.f); v.y = fmaxf(v.y, 0.f);
                    v.z = fmaxf(v.z, 0.f); v.w = fmaxf(v.w, 0.f);
                }
                *(float4*)&C[(size_t)(nb + j) * M + m0 + (ty << 2)] = v;
            }
        }
    }
}

// ---------------------------------------------------------------------------
// pack_whh: whh [768][256] -> wp4 float4-packed [64 k4][768 j]
// ---------------------------------------------------------------------------
__global__ __launch_bounds__(256) void pack_whh(
    const float* __restrict__ whh, float* __restrict__ wp4)
{
    const int idx = blockIdx.x * 256 + threadIdx.x;   // 0..49151
    const int j = idx % 768, k4 = idx / 768;
    const float4 v = *(const float4*)&whh[(size_t)j * 256 + k4 * 4];
    *(float4*)&wp4[(size_t)(k4 * 768 + j) * 4] = v;
}

// ---------------------------------------------------------------------------
// K3: GRU scan, NO grid sync.  64 blocks = 2 nets x 32 batch rows; each block
// owns the full 768-gate recurrence for its row.  (unchanged)
// ---------------------------------------------------------------------------
__global__ __launch_bounds__(768) void gru_scan2(
    const float* __restrict__ gi,
    const float* __restrict__ wp4_a, const float* __restrict__ wp4_c,
    const float* __restrict__ bhh_a, const float* __restrict__ bhh_c,
    const float* __restrict__ done,   // [4096]
    const float* __restrict__ h0,     // [2][32][256]
    float* __restrict__ hid,
    float* __restrict__ hT)
{
    const int net = blockIdx.x >> 5;
    const int b   = blockIdx.x & 31;
    const int tid = threadIdx.x;      // 0..767 = gate-row j

    __shared__ float hs[256];         // current h
    __shared__ float sb[768];         // per-gate pre-activations

    const float4* wp = (const float4*)(net ? wp4_c : wp4_a);
    const float*  bhh = net ? bhh_c : bhh_a;
    const float   bh  = bhh[tid];
    const float*  gib = gi + (size_t)net * TB * 768;

    if (tid < 256) hs[tid] = h0[net * 8192 + b * 256 + tid];
    __syncthreads();

    for (int t = 0; t < NT; t++) {
        const int   row = t * 32 + b;
        const float d1  = 1.f - done[row];

        float acc = 0.f;
        #pragma unroll 8
        for (int k4 = 0; k4 < 64; k4++) {
            const float4 w  = wp[k4 * 768 + tid];
            const float4 h4 = *(const float4*)&hs[k4 * 4];
            acc += w.x * h4.x + w.y * h4.y + w.z * h4.z + w.w * h4.w;
        }
        float s = d1 * acc + bh;
        if (tid < 512) s += gib[(size_t)row * 768 + tid];   // r,z add gi here
        sb[tid] = s;
        __syncthreads();

        if (tid < 256) {
            const float r   = 1.f / (1.f + expf(-sb[tid]));
            const float z   = 1.f / (1.f + expf(-sb[256 + tid]));
            const float gin = gib[(size_t)row * 768 + 512 + tid];
            const float n   = tanhf(gin + r * sb[512 + tid]);
            const float hm  = d1 * hs[tid];
            const float hnew = (1.f - z) * n + z * hm;
            hs[tid] = hnew;
            hid[((size_t)net * TB + row) * 256 + tid] = fmaxf(hnew, 0.f);
            if (t == NT - 1) hT[net * 8192 + b * 256 + tid] = hnew;
        }
        __syncthreads();
    }
}

// ---------------------------------------------------------------------------
// K5: heads — m2 arrives TRANSPOSED ([100][4096] per net).  (unchanged)
// ---------------------------------------------------------------------------
__global__ __launch_bounds__(256) void heads(
    const float* __restrict__ m2Ta, const float* __restrict__ m2Tc,
    const float* __restrict__ aw3, const float* __restrict__ ab3,
    const float* __restrict__ cw3, const float* __restrict__ cb3,
    const int* __restrict__ action,
    float* __restrict__ out)
{
    __shared__ float AW[700], AB[7], CW[100], CB1[1];
    const int tid = threadIdx.x;
    for (int f = tid; f < 700; f += 256) AW[f] = aw3[f];
    if (tid < 7)   AB[tid] = ab3[tid];
    if (tid < 100) CW[tid] = cw3[tid];
    if (tid == 0)  CB1[0] = cb3[0];
    __syncthreads();

    const int r = blockIdx.x * 256 + tid;

    float l[7];
    #pragma unroll
    for (int jj = 0; jj < 7; jj++) l[jj] = AB[jj];
    for (int k = 0; k < 100; k++) {
        const float mv = m2Ta[(size_t)k * TB + r];
        #pragma unroll
        for (int jj = 0; jj < 7; jj++) l[jj] += mv * AW[jj * 100 + k];
    }
    float mx = l[0];
    #pragma unroll
    for (int jj = 1; jj < 7; jj++) mx = fmaxf(mx, l[jj]);
    float se = 0.f;
    #pragma unroll
    for (int jj = 0; jj < 7; jj++) se += expf(l[jj] - mx);
    const float lse = logf(se);
    const int a = action[r];
    float ent = 0.f, lp_a = 0.f;
    #pragma unroll
    for (int jj = 0; jj < 7; jj++) {
        const float lp = l[jj] - mx - lse;
        ent -= expf(lp) * lp;
        if (jj == a) lp_a = lp;
    }

    float v = CB1[0];
    for (int k = 0; k < 100; k++) v += m2Tc[(size_t)k * TB + r] * CW[k];

    out[r]          = (float)a;
    out[TB + r]     = lp_a;
    out[2 * TB + r] = ent;
    out[3 * TB + r] = v;
}

// ---------------------------------------------------------------------------
extern "C" void kernel_launch(void* const* d_in, const int* in_sizes, int n_in,
                              void* d_out, int out_size, void* d_ws, size_t ws_size,
                              hipStream_t stream)
{
    const float* x     = (const float*)d_in[0];
    const float* gru0  = (const float*)d_in[1];
    const float* done  = (const float*)d_in[2];
    const int*   act   = (const int*)d_in[3];
    #define AIN(i) ((const float*)d_in[4 + (i)])
    #define CIN(i) ((const float*)d_in[20 + (i)])
    // per-net order: c1w,c1b,c2w,c2b,fw,fb,wih,whh,bih,bhh,h1w,h1b,h2w,h2b,h3w,h3b

    // Workspace (12,713,984 floats, same as before):
    // region1 (10,616,832 f): y2 during conv/FC phase; then gi+m1+m2T+wp4.
    // region2 ( 2,097,152 f): feats during FC/gi phase; then hid.
    float* ws = (float*)d_ws;
    float* region1 = ws;
    float* region2 = ws + (size_t)TB * 2592;

    float* y2    = region1;                         // [4096][2592]
    float* gi    = region1;                         // [2][4096][768] (after y2 dead)
    float* m1    = gi  + (size_t)2 * TB * 768;      // [2][4096][200]
    float* m2T   = m1  + (size_t)2 * TB * 200;      // [2][100][4096]
    float* wp4_a = m2T + (size_t)2 * TB * 100;      // [64][768][4] packed whh (actor)
    float* wp4_c = wp4_a + (size_t)64 * 768 * 4;    // same (critic)

    float* feats = region2;                         // [2][4096][256]
    float* hid   = region2;                         // [2][4096][256] (after feats dead)

    float* feats_c = feats + (size_t)TB * 256;
    float* gi_c    = gi    + (size_t)TB * 768;
    float* m1_c    = m1    + (size_t)TB * 200;
    float* m2T_c   = m2T   + (size_t)TB * 100;
    float* hid_c   = hid   + (size_t)TB * 256;

    // ---- actor CNN + FC ----
    conv_front2<<<TB, 256, 0, stream>>>(x, AIN(0), AIN(1), AIN(2), AIN(3), y2);
    gemm64<<<dim3(64, 4), 256, 0, stream>>>(y2, AIN(4), AIN(5), feats,
                                            TB, 256, 2592, 1, 0, 0);
    // ---- critic CNN + FC (reuse y2) ----
    conv_front2<<<TB, 256, 0, stream>>>(x, CIN(0), CIN(1), CIN(2), CIN(3), y2);
    gemm64<<<dim3(64, 4), 256, 0, stream>>>(y2, CIN(4), CIN(5), feats_c,
                                            TB, 256, 2592, 1, 0, 0);

    // ---- y2 dead: pack whh for the scan; gi row-major (bih added) ----
    pack_whh<<<192, 256, 0, stream>>>(AIN(7), wp4_a);
    pack_whh<<<192, 256, 0, stream>>>(CIN(7), wp4_c);
    gemm64<<<dim3(64, 12), 256, 0, stream>>>(feats, AIN(6), AIN(8), gi,
                                             TB, 768, 256, 0, 0, 0);
    gemm64<<<dim3(64, 12), 256, 0, stream>>>(feats_c, CIN(6), CIN(8), gi_c,
                                             TB, 768, 256, 0, 0, 0);

    // ---- GRU scan: 64 independent blocks, no grid sync ----
    float* out = (float*)d_out;
    gru_scan2<<<64, 768, 0, stream>>>(gi, wp4_a, wp4_c, AIN(9), CIN(9),
                                      done, gru0, hid, out + 4 * TB);

    // ---- MLPs: m1 reads hid row-major; m2 written transposed for heads ----
    gemm64<<<dim3(64, 4), 256, 0, stream>>>(hid, AIN(10), AIN(11), m1,
                                            TB, 200, 256, 1, 0, 0);
    gemm64<<<dim3(64, 4), 256, 0, stream>>>(hid_c, CIN(10), CIN(11), m1_c,
                                            TB, 200, 256, 1, 0, 0);
    gemm64<<<dim3(64, 2), 256, 0, stream>>>(m1, AIN(12), AIN(13), m2T,
                                            TB, 100, 200, 1, 0, 1);
    gemm64<<<dim3(64, 2), 256, 0, stream>>>(m1_c, CIN(12), CIN(13), m2T_c,
                                            TB, 100, 200, 1, 0, 1);

    // ---- heads ----
    heads<<<TB / 256, 256, 0, stream>>>(m2T, m2T_c, AIN(14), AIN(15),
                                        CIN(14), CIN(15), act, out);
}